// Round 19
// baseline (295.768 us; speedup 1.0000x reference)
//
#include <hip/hip_runtime.h>
#include <hip/hip_bf16.h>
#include <math.h>

typedef __attribute__((ext_vector_type(4))) float f32x4;
typedef __attribute__((ext_vector_type(2))) float f32x2;
typedef __attribute__((ext_vector_type(8))) short short8;
typedef __attribute__((ext_vector_type(4))) unsigned int uint4v;
typedef unsigned short ushort_t;
typedef unsigned int uint_t;

__device__ __forceinline__ float b2f(unsigned short u) {
    unsigned int v = ((unsigned int)u) << 16;
    return __uint_as_float(v);
}
__device__ __forceinline__ unsigned short f2b(float f) {
    unsigned int x = __float_as_uint(f);
    unsigned int r = (x + 0x7fffu + ((x >> 16) & 1u)) >> 16;
    return (unsigned short)r;
}

// column permutation for MFMA-layout PQ / X-agg storage
__device__ __forceinline__ int permc(int d) { return ((d & 15) << 3) | (d >> 4); }

// ---------------------------------------------------------------- merged prep
// zero counts | pack WbT | pack WcT (K-permuted) | pack W3P bf16 | conv h->X
__global__ void prep_kernel(const float* __restrict__ W_pre,
                            const float* __restrict__ W_post,
                            const float* __restrict__ h,
                            int* __restrict__ counts,
                            ushort_t* __restrict__ WbT,
                            ushort_t* __restrict__ WcT,
                            ushort_t* __restrict__ W3P,
                            ushort_t* __restrict__ X, int Nn) {
    int i = blockIdx.x * 256 + threadIdx.x;
    int n0 = Nn + 1;
    if (i < n0) { counts[i] = 0; return; }
    i -= n0;
    if (i < 256 * 128) {
        int nn = i >> 7, k = i & 127;
        float v = (nn < 128) ? W_pre[k * 128 + nn] : W_pre[(128 + k) * 128 + (nn - 128)];
        WbT[i] = f2b(v);
        return;
    }
    i -= 256 * 128;
    if (i < 384 * 896) {
        int nn = i / 896, k = i % 896;
        float v;
        if (k < 128) {
            v = (nn < 128) ? W_post[k * 128 + nn] : 0.f;
        } else {
            int ka = k - 128;
            int pp = ka & 127;
            int d = ((pp & 7) << 4) | (pp >> 3);      // inverse of permc
            ka = (ka & ~127) | d;
            if (nn < 128)      v = W_post[(128 + ka) * 128 + nn];
            else if (nn < 256) v = W_post[(896 + ka) * 128 + (nn - 128)];
            else               v = W_post[(1664 + ka) * 128 + (nn - 256)];
        }
        WcT[i] = f2b(v);
        return;
    }
    i -= 384 * 896;
    if (i < 128 * 16) {
        int d = i >> 4, k = i & 15;
        W3P[d * 16 + k] = f2b(W_pre[(256 + k) * 128 + d]);
        return;
    }
    i -= 128 * 16;
    if (i < Nn * 32) {
        int n = i >> 5, c4 = (i & 31) * 4;
        float4 hv = *(const float4*)&h[(size_t)n * 128 + c4];
        ushort4 o;
        o.x = f2b(hv.x); o.y = f2b(hv.y); o.z = f2b(hv.z); o.w = f2b(hv.w);
        *(ushort4*)&X[(size_t)n * 896 + c4] = o;
    }
}

// ---------------------------------------------------------------- CSR build
__global__ void hist_kernel(const int* __restrict__ dst, int* __restrict__ counts, int E) {
    int i = blockIdx.x * 256 + threadIdx.x;
    if (i < E) atomicAdd(&counts[dst[i]], 1);
}

// ---- 3-phase parallel exclusive scan ----
__global__ __launch_bounds__(256) void scanA_kernel(const int* __restrict__ counts,
                                                    int* __restrict__ localscan,
                                                    int* __restrict__ blocksum, int Nn) {
    __shared__ int part[256];
    int b = blockIdx.x, t = threadIdx.x;
    int idx = b * 1024 + t * 4;
    int4 v = (idx + 3 < Nn) ? *(const int4*)&counts[idx]
             : make_int4(idx < Nn ? counts[idx] : 0,
                         idx + 1 < Nn ? counts[idx + 1] : 0,
                         idx + 2 < Nn ? counts[idx + 2] : 0,
                         idx + 3 < Nn ? counts[idx + 3] : 0);
    int s1 = v.x, s2 = v.x + v.y, s3 = s2 + v.z, tot = s3 + v.w;
    part[t] = tot;
    __syncthreads();
    for (int off = 1; off < 256; off <<= 1) {
        int x = part[t];
        int u = (t >= off) ? part[t - off] : 0;
        __syncthreads();
        part[t] = x + u;
        __syncthreads();
    }
    int pre = (t > 0) ? part[t - 1] : 0;
    if (idx < Nn) {
        if (idx + 3 < Nn) {
            *(int4*)&localscan[idx] = make_int4(pre, pre + s1, pre + s2, pre + s3);
        } else {
            localscan[idx] = pre;
            if (idx + 1 < Nn) localscan[idx + 1] = pre + s1;
            if (idx + 2 < Nn) localscan[idx + 2] = pre + s2;
        }
    }
    if (t == 255) blocksum[b] = part[255];
}

__global__ __launch_bounds__(64) void scanB_kernel(int* __restrict__ blocksum, int nb) {
    __shared__ int sh[64];
    int t = threadIdx.x;
    int v = (t < nb) ? blocksum[t] : 0;
    sh[t] = v;
    __syncthreads();
    for (int off = 1; off < 64; off <<= 1) {
        int x = sh[t];
        int u = (t >= off) ? sh[t - off] : 0;
        __syncthreads();
        sh[t] = x + u;
        __syncthreads();
    }
    int pre = (t > 0) ? sh[t - 1] : 0;
    if (t < nb) blocksum[t] = pre;
    if (t == 63) blocksum[nb] = sh[63];
}

__global__ void scanC_kernel(int* __restrict__ localscan, const int* __restrict__ blocksum,
                             int* __restrict__ counts, int Nn, int nb) {
    int i = blockIdx.x * 256 + threadIdx.x;
    if (i < Nn) {
        int o = localscan[i] + blocksum[blockIdx.x >> 2];
        counts[i] = o;
        localscan[i] = o;   // cursors
    }
    if (i == 0) counts[Nn] = blocksum[nb];
}

// scatter: one aligned 16B record per CSR slot: {src, eid, eig_src_bits, 0}
__global__ void scatter_kernel(const int* __restrict__ dst, const int* __restrict__ src,
                               const float* __restrict__ eig, int* __restrict__ cursors,
                               int4* __restrict__ esl, int E) {
    int i = blockIdx.x * 256 + threadIdx.x;
    if (i < E) {
        int v = dst[i];
        int p = atomicAdd(&cursors[v], 1);
        int s = src[i];
        esl[p] = make_int4(s, i, __float_as_int(eig[s * 2 + 1]), 0);
    }
}

// ---------------------------------------------------------------- bf16 MFMA GEMM (B^T)
// C[M,N] = A[M,K](bf16,lda) @ Bt[N,K]^T.  128x128 tile, BK=64, 4 waves.
// PERM: permute output columns by permc within each 128-block (PQ layout).
template <int OUT_BF16, int PERM>
__global__ __launch_bounds__(256) void gemm_bt(const ushort_t* __restrict__ A, int lda,
                                               const ushort_t* __restrict__ Bt, int ldb,
                                               void* __restrict__ Cv, int ldc,
                                               int M, int K, int NT) {
    __shared__ ushort_t ldsbuf[2 * 128 * 64];
    const int tid = threadIdx.x, wid = tid >> 6, lane = tid & 63;
    int nwg = gridDim.x;
    int orig = blockIdx.x;
    int q8 = nwg >> 3, r8 = nwg & 7;
    int xcd = orig & 7, local = orig >> 3;
    int wg = (xcd < r8 ? xcd * (q8 + 1) : r8 * (q8 + 1) + (xcd - r8) * q8) + local;
    const int m0 = (wg / NT) * 128, n0 = (wg % NT) * 128;
    f32x4 acc[4][4] = {};
    const int wrow = (wid >> 1) * 64, wcol = (wid & 1) * 64;

    for (int kt = 0; kt < K; kt += 64) {
#pragma unroll
        for (int rnd = 0; rnd < 4; ++rnd) {
            int libase = rnd * 256 + wid * 64;
            {
                int lc = libase + lane;
                int r = lc >> 3, cs = lc & 7;
                int c = cs ^ (r & 7);
                int row = m0 + r; row = row < M ? row : M - 1;
                const ushort_t* g = A + (size_t)row * lda + (kt + c * 8);
                __builtin_amdgcn_global_load_lds(
                    (const __attribute__((address_space(1))) unsigned int*)g,
                    (__attribute__((address_space(3))) unsigned int*)&ldsbuf[(size_t)libase * 8],
                    16, 0, 0);
            }
            {
                int lc = libase + lane;
                int r = lc >> 3, cs = lc & 7;
                int c = cs ^ (r & 7);
                const ushort_t* g = Bt + (size_t)(n0 + r) * ldb + (kt + c * 8);
                __builtin_amdgcn_global_load_lds(
                    (const __attribute__((address_space(1))) unsigned int*)g,
                    (__attribute__((address_space(3))) unsigned int*)&ldsbuf[8192 + (size_t)libase * 8],
                    16, 0, 0);
            }
        }
        __syncthreads();
#pragma unroll
        for (int kk = 0; kk < 2; ++kk) {
            short8 af[4], bfr[4];
#pragma unroll
            for (int f = 0; f < 4; ++f) {
                int r = wrow + f * 16 + (lane & 15);
                int c16 = kk * 4 + (lane >> 4);
                int ch = r * 8 + (c16 ^ (r & 7));
                af[f] = *(const short8*)&ldsbuf[ch * 8];
            }
#pragma unroll
            for (int f = 0; f < 4; ++f) {
                int r = wcol + f * 16 + (lane & 15);
                int c16 = kk * 4 + (lane >> 4);
                int ch = r * 8 + (c16 ^ (r & 7));
                bfr[f] = *(const short8*)&ldsbuf[8192 + ch * 8];
            }
#pragma unroll
            for (int i = 0; i < 4; ++i)
#pragma unroll
                for (int j = 0; j < 4; ++j)
                    acc[i][j] = __builtin_amdgcn_mfma_f32_16x16x32_bf16(af[i], bfr[j], acc[i][j], 0, 0, 0);
        }
        __syncthreads();
    }
#pragma unroll
    for (int i = 0; i < 4; ++i)
#pragma unroll
        for (int j = 0; j < 4; ++j)
#pragma unroll
            for (int q = 0; q < 4; ++q) {
                int row = m0 + wrow + i * 16 + (lane >> 4) * 4 + q;
                int col = n0 + wcol + j * 16 + (lane & 15);
                if (PERM) col = (col & ~127) | permc(col & 127);
                if (row < M) {
                    if (OUT_BF16) ((ushort_t*)Cv)[(size_t)row * ldc + col] = f2b(acc[i][j][q]);
                    else          ((float*)Cv)[(size_t)row * ldc + col] = acc[i][j][q];
                }
            }
}

// ---------------------------------------------------------------- agg via MFMA
// one wave per node; rounds of 16 edges. 8x mfma_f32_16x16x32_bf16 compute
// ew = ef@W3 (K padded to 32 with zero lanes). Lane (c=lane&15, eg=lane>>4)
// holds edges eg*4+q, dims b*16+c. PQ stored permc-permuted -> 16B row loads.
// Aggregates reduced across e-groups by ^16/^32 butterfly.
#define RLI(v, l) __builtin_amdgcn_readlane((v), (l))
__global__ __launch_bounds__(256) void agg_mfma(
    const ushort_t* __restrict__ PQ, ushort_t* __restrict__ X,
    const int4* __restrict__ esl, const int* __restrict__ offs,
    const float* __restrict__ eig, const float* __restrict__ h,
    const float* __restrict__ ef, const ushort_t* __restrict__ W3P,
    const float* __restrict__ b_pre, float* __restrict__ scal, int Nn) {
    int tid = threadIdx.x;
    int wid = tid >> 6, lane = tid & 63;
    int n = blockIdx.x * 4 + wid;
    if (n >= Nn) return;
    int off0 = offs[n], off1 = offs[n + 1];
    int deg = off1 - off0;
    int c = lane & 15, eg = lane >> 4;

    const uint4v zu = {0u, 0u, 0u, 0u};
    const short8 zf = __builtin_bit_cast(short8, zu);

    // B fragments: W3T[dim=b*16+c][k=8*eg..+7]; zero for eg>=2 (K padding)
    short8 w3f[8];
#pragma unroll
    for (int b = 0; b < 8; ++b)
        w3f[b] = (eg < 2) ? *(const short8*)&W3P[(b * 16 + c) * 16 + eg * 8] : zf;

    // qb[b] = Q[n][b*16+c] + b_pre[b*16+c]  (Q stored permuted: pos 128+c*8+b)
    float qb[8];
    {
        short8 qv = *(const short8*)&PQ[(size_t)n * 256 + 128 + c * 8];
        uint4v qu = __builtin_bit_cast(uint4v, qv);
#pragma unroll
        for (int p = 0; p < 4; ++p) {
            uint_t u = qu[p];
            qb[2 * p]     = __uint_as_float(u << 16)          + b_pre[(2 * p) * 16 + c];
            qb[2 * p + 1] = __uint_as_float(u & 0xffff0000u)  + b_pre[(2 * p + 1) * 16 + c];
        }
    }
    float eigd = eig[n * 2 + 1];

    float s[8] = {}, ssq[8] = {}, av[8] = {}, dv[8] = {};
    float mx[8], mn[8];
#pragma unroll
    for (int b = 0; b < 8; ++b) { mx[b] = -1e30f; mn[b] = 1e30f; }
    float den = 0.f;
    const f32x4 zeroc = {0.f, 0.f, 0.f, 0.f};

    for (int q0 = off0; q0 < off1; q0 += 16) {
        int lim = off1 - 1;
        int slot = q0 + c;
        if (slot > lim) slot = lim;
        int4 rc = esl[slot];

        // A fragment: edge = c, k = 8*eg..+7 (eg<2), zeros otherwise
        short8 af = zf;
        if (eg < 2) {
            const float* ep = ef + (size_t)rc.y * 16 + eg * 8;
            float4 e0 = *(const float4*)ep;
            float4 e1 = *(const float4*)(ep + 4);
            uint4v ua;
            ua[0] = __builtin_amdgcn_perm(__float_as_uint(e0.y), __float_as_uint(e0.x), 0x07060302u);
            ua[1] = __builtin_amdgcn_perm(__float_as_uint(e0.w), __float_as_uint(e0.z), 0x07060302u);
            ua[2] = __builtin_amdgcn_perm(__float_as_uint(e1.y), __float_as_uint(e1.x), 0x07060302u);
            ua[3] = __builtin_amdgcn_perm(__float_as_uint(e1.w), __float_as_uint(e1.z), 0x07060302u);
            af = __builtin_bit_cast(short8, ua);
        }

        f32x4 acc[8];
#pragma unroll
        for (int b = 0; b < 8; ++b)
            acc[b] = __builtin_amdgcn_mfma_f32_16x16x32_bf16(af, w3f[b], zeroc, 0, 0, 0);

#pragma unroll
        for (int q = 0; q < 4; ++q) {
            int ei = eg * 4 + q;
            int sj = __shfl(rc.x, ei);
            float ddr = __int_as_float(__shfl(rc.z, ei)) - eigd;
            bool valid = (q0 + ei) < off1;
            float dd = valid ? ddr : 0.f;
            float ad = fabsf(dd);
            short8 pw = *(const short8*)&PQ[(size_t)sj * 256 + c * 8];
            uint4v pu = __builtin_bit_cast(uint4v, pw);
#pragma unroll
            for (int p = 0; p < 4; ++p) {
                uint_t u = pu[p];
                float m0 = acc[2 * p][q]     + __uint_as_float(u << 16)         + qb[2 * p];
                float m1 = acc[2 * p + 1][q] + __uint_as_float(u & 0xffff0000u) + qb[2 * p + 1];
                mx[2 * p] = fmaxf(mx[2 * p], m0); mn[2 * p] = fminf(mn[2 * p], m0);
                mx[2 * p + 1] = fmaxf(mx[2 * p + 1], m1); mn[2 * p + 1] = fminf(mn[2 * p + 1], m1);
                float z0 = valid ? m0 : 0.f;
                float z1 = valid ? m1 : 0.f;
                s[2 * p] += z0; ssq[2 * p] = fmaf(z0, z0, ssq[2 * p]);
                av[2 * p] = fmaf(z0, ad, av[2 * p]); dv[2 * p] = fmaf(z0, dd, dv[2 * p]);
                s[2 * p + 1] += z1; ssq[2 * p + 1] = fmaf(z1, z1, ssq[2 * p + 1]);
                av[2 * p + 1] = fmaf(z1, ad, av[2 * p + 1]); dv[2 * p + 1] = fmaf(z1, dd, dv[2 * p + 1]);
            }
            den += ad;
        }
    }

    // butterfly reduce across the 4 e-groups (lanes ^16, ^32)
#pragma unroll
    for (int b = 0; b < 8; ++b) {
        s[b] += __shfl_xor(s[b], 16);   s[b] += __shfl_xor(s[b], 32);
        ssq[b] += __shfl_xor(ssq[b], 16); ssq[b] += __shfl_xor(ssq[b], 32);
        av[b] += __shfl_xor(av[b], 16); av[b] += __shfl_xor(av[b], 32);
        dv[b] += __shfl_xor(dv[b], 16); dv[b] += __shfl_xor(dv[b], 32);
        mx[b] = fmaxf(mx[b], __shfl_xor(mx[b], 16)); mx[b] = fmaxf(mx[b], __shfl_xor(mx[b], 32));
        mn[b] = fminf(mn[b], __shfl_xor(mn[b], 16)); mn[b] = fminf(mn[b], __shfl_xor(mn[b], 32));
    }
    den += __shfl_xor(den, 16); den += __shfl_xor(den, 32);

    bool has = deg > 0;
    float inv = has ? 1.f / (float)deg : 0.f;
    float idn = has ? 1.f / (den + 1e-8f) : 0.f;
    size_t xb = (size_t)n * 896 + 128;

    {   // aggregate a = eg (0:mean 1:max 2:min 3:std)
        int a = eg;
        ushort_t ob[8];
#pragma unroll
        for (int b = 0; b < 8; ++b) {
            float val;
            if (a == 0)      val = s[b] * inv;
            else if (a == 1) val = mx[b];
            else if (a == 2) val = mn[b];
            else {
                float mean = s[b] * inv;
                float var = fmaxf(ssq[b] * inv - mean * mean, 0.f);
                val = sqrtf(var + 1e-5f);
            }
            ob[b] = has ? f2b(val) : (ushort_t)0;
        }
        uint4v ou;
        ou[0] = (uint_t)ob[0] | ((uint_t)ob[1] << 16);
        ou[1] = (uint_t)ob[2] | ((uint_t)ob[3] << 16);
        ou[2] = (uint_t)ob[4] | ((uint_t)ob[5] << 16);
        ou[3] = (uint_t)ob[6] | ((uint_t)ob[7] << 16);
        *(uint4v*)&X[xb + (size_t)a * 128 + c * 8] = ou;
    }
    if (eg < 2) {   // aggregate a = 4+eg (4:dir_av 5:dir_dx)
        int a = 4 + eg;
        ushort_t ob[8];
#pragma unroll
        for (int b = 0; b < 8; ++b) {
            float val;
            if (a == 4) val = av[b] * idn;
            else        val = dv[b] * idn - h[(size_t)n * 128 + b * 16 + c];
            ob[b] = has ? f2b(val) : (ushort_t)0;
        }
        uint4v ou;
        ou[0] = (uint_t)ob[0] | ((uint_t)ob[1] << 16);
        ou[1] = (uint_t)ob[2] | ((uint_t)ob[3] << 16);
        ou[2] = (uint_t)ob[4] | ((uint_t)ob[5] << 16);
        ou[3] = (uint_t)ob[6] | ((uint_t)ob[7] << 16);
        *(uint4v*)&X[xb + (size_t)a * 128 + c * 8] = ou;
    }
    if (lane == 0) {
        float degc = has ? (float)deg : 1.f;
        float logd = logf(degc + 1.f);
        scal[n * 2] = logd * (1.f / 2.772588722239781f);
        scal[n * 2 + 1] = 2.772588722239781f / logd;
    }
}

// ---------------------------------------------------------------- epilogue (bf16 O3)
__global__ __launch_bounds__(256) void epilogue_kernel(
    const ushort_t* __restrict__ O3, const float* __restrict__ h,
    const float* __restrict__ snorm, const float* __restrict__ scal,
    const float* __restrict__ b_post, float* __restrict__ out, int Nn) {
    int g = blockIdx.x * 256 + threadIdx.x;
    if (g >= Nn * 32) return;
    int n = g >> 5, c4 = (g & 31) * 4;
    float a = scal[n * 2], b = scal[n * 2 + 1], sn = snorm[n];
    const ushort_t* base = O3 + (size_t)n * 384 + c4;
    ushort4 u1 = *(const ushort4*)base;
    ushort4 u2 = *(const ushort4*)(base + 128);
    ushort4 u3 = *(const ushort4*)(base + 256);
    float4 bp = *(const float4*)&b_post[c4];
    float4 hv = *(const float4*)&h[(size_t)n * 128 + c4];
    float4 r;
    r.x = fmaxf((b2f(u1.x) + a * b2f(u2.x) + b * b2f(u3.x) + bp.x) * sn, 0.f) + hv.x;
    r.y = fmaxf((b2f(u1.y) + a * b2f(u2.y) + b * b2f(u3.y) + bp.y) * sn, 0.f) + hv.y;
    r.z = fmaxf((b2f(u1.z) + a * b2f(u2.z) + b * b2f(u3.z) + bp.z) * sn, 0.f) + hv.z;
    r.w = fmaxf((b2f(u1.w) + a * b2f(u2.w) + b * b2f(u3.w) + bp.w) * sn, 0.f) + hv.w;
    *(float4*)&out[(size_t)n * 128 + c4] = r;
}

// ---------------------------------------------------------------- launch
extern "C" void kernel_launch(void* const* d_in, const int* in_sizes, int n_in,
                              void* d_out, int out_size, void* d_ws, size_t ws_size,
                              hipStream_t stream) {
    const float* h      = (const float*)d_in[0];
    const float* ef     = (const float*)d_in[1];
    const float* eig    = (const float*)d_in[2];
    const float* snorm  = (const float*)d_in[3];
    const int*   src    = (const int*)d_in[4];
    const int*   dst    = (const int*)d_in[5];
    const float* W_pre  = (const float*)d_in[6];
    const float* b_pre  = (const float*)d_in[7];
    const float* W_post = (const float*)d_in[8];
    const float* b_post = (const float*)d_in[9];
    int Nn = in_sizes[0] / 128;
    int E  = in_sizes[4];
    float* out = (float*)d_out;

    char* ws = (char*)d_ws;
    size_t off = 0;
    auto alloc = [&](size_t bytes) {
        size_t o = off;
        off = (off + bytes + 255) & ~(size_t)255;
        return o;
    };
    size_t o_counts  = alloc(((size_t)Nn + 1) * 4);
    size_t o_cursors = alloc((size_t)Nn * 4);
    size_t o_bsum    = alloc(65 * 4);
    size_t o_esl     = alloc((size_t)E * 16);
    size_t o_PQ      = alloc((size_t)Nn * 256 * 2);
    size_t o_X       = alloc((size_t)Nn * 896 * 2);
    size_t o_O3      = alloc((size_t)Nn * 384 * 2);
    size_t o_scal    = alloc((size_t)Nn * 2 * 4);
    size_t o_wb      = alloc(256 * 128 * 2);
    size_t o_wc      = alloc(384 * 896 * 2);
    size_t o_w3p     = alloc(128 * 16 * 2);
    (void)ws_size;

    int*      counts  = (int*)(ws + o_counts);
    int*      cursors = (int*)(ws + o_cursors);
    int*      bsum    = (int*)(ws + o_bsum);
    int4*     esl     = (int4*)(ws + o_esl);
    ushort_t* PQ      = (ushort_t*)(ws + o_PQ);
    ushort_t* X       = (ushort_t*)(ws + o_X);
    ushort_t* O3      = (ushort_t*)(ws + o_O3);
    float*    scal    = (float*)(ws + o_scal);
    ushort_t* WbT     = (ushort_t*)(ws + o_wb);
    ushort_t* WcT     = (ushort_t*)(ws + o_wc);
    ushort_t* W3P     = (ushort_t*)(ws + o_w3p);

    int prep_items = (Nn + 1) + 256 * 128 + 384 * 896 + 128 * 16 + Nn * 32;
    prep_kernel<<<(prep_items + 255) / 256, 256, 0, stream>>>(W_pre, W_post, h,
                                                              counts, WbT, WcT, W3P, X, Nn);
    hist_kernel<<<(E + 255) / 256, 256, 0, stream>>>(dst, counts, E);
    int nb = (Nn + 1023) / 1024;
    scanA_kernel<<<nb, 256, 0, stream>>>(counts, cursors, bsum, Nn);
    scanB_kernel<<<1, 64, 0, stream>>>(bsum, nb);
    scanC_kernel<<<(Nn + 255) / 256, 256, 0, stream>>>(cursors, bsum, counts, Nn, nb);
    scatter_kernel<<<(E + 255) / 256, 256, 0, stream>>>(dst, src, eig, cursors, esl, E);

    int mt = (Nn + 127) / 128;
    gemm_bt<1, 1><<<mt * 2, 256, 0, stream>>>(X, 896, WbT, 128, (void*)PQ, 256, Nn, 128, 2);

    agg_mfma<<<(Nn + 3) / 4, 256, 0, stream>>>(PQ, X, esl, counts, eig, h, ef,
                                               W3P, b_pre, scal, Nn);

    gemm_bt<1, 0><<<mt * 3, 256, 0, stream>>>(X, 896, WcT, 896, (void*)O3, 384, Nn, 896, 3);

    epilogue_kernel<<<(Nn * 32 + 255) / 256, 256, 0, stream>>>(O3, h, snorm, scal, b_post,
                                                               out, Nn);
}

// Round 20
// 226.225 us; speedup vs baseline: 1.3074x; 1.3074x over previous
//
#include <hip/hip_runtime.h>
#include <hip/hip_bf16.h>
#include <math.h>

typedef __attribute__((ext_vector_type(4))) float f32x4;
typedef __attribute__((ext_vector_type(2))) float f32x2;
typedef __attribute__((ext_vector_type(8))) short short8;
typedef unsigned short ushort_t;
typedef unsigned int uint_t;

__device__ __forceinline__ float b2f(unsigned short u) {
    unsigned int v = ((unsigned int)u) << 16;
    return __uint_as_float(v);
}
__device__ __forceinline__ unsigned short f2b(float f) {
    unsigned int x = __float_as_uint(f);
    unsigned int r = (x + 0x7fffu + ((x >> 16) & 1u)) >> 16;
    return (unsigned short)r;
}

// ---------------------------------------------------------------- merged prep
// one dispatch: zero counts | pack WbT | pack WcT | conv h->X(:,0:128)
__global__ void prep_kernel(const float* __restrict__ W_pre,
                            const float* __restrict__ W_post,
                            const float* __restrict__ h,
                            int* __restrict__ counts,
                            ushort_t* __restrict__ WbT,
                            ushort_t* __restrict__ WcT,
                            ushort_t* __restrict__ X, int Nn) {
    int i = blockIdx.x * 256 + threadIdx.x;
    int n0 = Nn + 1;
    if (i < n0) { counts[i] = 0; return; }
    i -= n0;
    if (i < 256 * 128) {
        int nn = i >> 7, k = i & 127;
        float v = (nn < 128) ? W_pre[k * 128 + nn] : W_pre[(128 + k) * 128 + (nn - 128)];
        WbT[i] = f2b(v);
        return;
    }
    i -= 256 * 128;
    if (i < 384 * 896) {
        int nn = i / 896, k = i % 896;
        float v;
        if (k < 128) {
            v = (nn < 128) ? W_post[k * 128 + nn] : 0.f;
        } else {
            int ka = k - 128;
            if (nn < 128)      v = W_post[(128 + ka) * 128 + nn];
            else if (nn < 256) v = W_post[(896 + ka) * 128 + (nn - 128)];
            else               v = W_post[(1664 + ka) * 128 + (nn - 256)];
        }
        WcT[i] = f2b(v);
        return;
    }
    i -= 384 * 896;
    if (i < Nn * 32) {
        int n = i >> 5, c4 = (i & 31) * 4;
        float4 hv = *(const float4*)&h[(size_t)n * 128 + c4];
        ushort4 o;
        o.x = f2b(hv.x); o.y = f2b(hv.y); o.z = f2b(hv.z); o.w = f2b(hv.w);
        *(ushort4*)&X[(size_t)n * 896 + c4] = o;
    }
}

// ---------------------------------------------------------------- CSR build
__global__ void hist_kernel(const int* __restrict__ dst, int* __restrict__ counts, int E) {
    int i = blockIdx.x * 256 + threadIdx.x;
    if (i < E) atomicAdd(&counts[dst[i]], 1);
}

// ---- 3-phase parallel exclusive scan (Nn <= 64*1024) ----
// A: per-1024-block local exclusive scan -> localscan (cursors buf), block totals
__global__ __launch_bounds__(256) void scanA_kernel(const int* __restrict__ counts,
                                                    int* __restrict__ localscan,
                                                    int* __restrict__ blocksum, int Nn) {
    __shared__ int part[256];
    int b = blockIdx.x, t = threadIdx.x;
    int idx = b * 1024 + t * 4;
    int4 v = (idx + 3 < Nn) ? *(const int4*)&counts[idx]
             : make_int4(idx < Nn ? counts[idx] : 0,
                         idx + 1 < Nn ? counts[idx + 1] : 0,
                         idx + 2 < Nn ? counts[idx + 2] : 0,
                         idx + 3 < Nn ? counts[idx + 3] : 0);
    int s1 = v.x, s2 = v.x + v.y, s3 = s2 + v.z, tot = s3 + v.w;
    part[t] = tot;
    __syncthreads();
    for (int off = 1; off < 256; off <<= 1) {
        int x = part[t];
        int u = (t >= off) ? part[t - off] : 0;
        __syncthreads();
        part[t] = x + u;
        __syncthreads();
    }
    int pre = (t > 0) ? part[t - 1] : 0;
    if (idx < Nn) {
        if (idx + 3 < Nn) {
            *(int4*)&localscan[idx] = make_int4(pre, pre + s1, pre + s2, pre + s3);
        } else {
            localscan[idx] = pre;
            if (idx + 1 < Nn) localscan[idx + 1] = pre + s1;
            if (idx + 2 < Nn) localscan[idx + 2] = pre + s2;
        }
    }
    if (t == 255) blocksum[b] = part[255];
}

// B: single small block scans the (<=64) block totals; blocksum[nb] = grand total
__global__ __launch_bounds__(64) void scanB_kernel(int* __restrict__ blocksum, int nb) {
    __shared__ int sh[64];
    int t = threadIdx.x;
    int v = (t < nb) ? blocksum[t] : 0;
    sh[t] = v;
    __syncthreads();
    for (int off = 1; off < 64; off <<= 1) {
        int x = sh[t];
        int u = (t >= off) ? sh[t - off] : 0;
        __syncthreads();
        sh[t] = x + u;
        __syncthreads();
    }
    int pre = (t > 0) ? sh[t - 1] : 0;
    if (t < nb) blocksum[t] = pre;
    if (t == 63) blocksum[nb] = sh[63];
}

// C: add block offsets -> counts (offsets) and cursors
__global__ void scanC_kernel(int* __restrict__ localscan, const int* __restrict__ blocksum,
                             int* __restrict__ counts, int Nn, int nb) {
    int i = blockIdx.x * 256 + threadIdx.x;
    if (i < Nn) {
        int o = localscan[i] + blocksum[blockIdx.x >> 2];
        counts[i] = o;
        localscan[i] = o;   // cursors
    }
    if (i == 0) counts[Nn] = blocksum[nb];
}

// scatter: one aligned 16B record per CSR slot: {src, eid, eig_src_bits, 0}
__global__ void scatter_kernel(const int* __restrict__ dst, const int* __restrict__ src,
                               const float* __restrict__ eig, int* __restrict__ cursors,
                               int4* __restrict__ esl, int E) {
    int i = blockIdx.x * 256 + threadIdx.x;
    if (i < E) {
        int v = dst[i];
        int p = atomicAdd(&cursors[v], 1);
        int s = src[i];
        esl[p] = make_int4(s, i, __float_as_int(eig[s * 2 + 1]), 0);
    }
}

// ---------------------------------------------------------------- bf16 MFMA GEMM (B^T)
// C[M,N] = A[M,K](bf16,lda) @ Bt[N,K]^T(bf16,ldb=K).  128x128 tile, BK=64, 4 waves.
template <int OUT_BF16>
__global__ __launch_bounds__(256) void gemm_bt(const ushort_t* __restrict__ A, int lda,
                                               const ushort_t* __restrict__ Bt, int ldb,
                                               void* __restrict__ Cv, int ldc,
                                               int M, int K, int NT) {
    __shared__ ushort_t ldsbuf[2 * 128 * 64];
    const int tid = threadIdx.x, wid = tid >> 6, lane = tid & 63;
    int nwg = gridDim.x;
    int orig = blockIdx.x;
    int q8 = nwg >> 3, r8 = nwg & 7;
    int xcd = orig & 7, local = orig >> 3;
    int wg = (xcd < r8 ? xcd * (q8 + 1) : r8 * (q8 + 1) + (xcd - r8) * q8) + local;
    const int m0 = (wg / NT) * 128, n0 = (wg % NT) * 128;
    f32x4 acc[4][4] = {};
    const int wrow = (wid >> 1) * 64, wcol = (wid & 1) * 64;

    for (int kt = 0; kt < K; kt += 64) {
#pragma unroll
        for (int rnd = 0; rnd < 4; ++rnd) {
            int libase = rnd * 256 + wid * 64;
            {
                int lc = libase + lane;
                int r = lc >> 3, cs = lc & 7;
                int c = cs ^ (r & 7);
                int row = m0 + r; row = row < M ? row : M - 1;
                const ushort_t* g = A + (size_t)row * lda + (kt + c * 8);
                __builtin_amdgcn_global_load_lds(
                    (const __attribute__((address_space(1))) unsigned int*)g,
                    (__attribute__((address_space(3))) unsigned int*)&ldsbuf[(size_t)libase * 8],
                    16, 0, 0);
            }
            {
                int lc = libase + lane;
                int r = lc >> 3, cs = lc & 7;
                int c = cs ^ (r & 7);
                const ushort_t* g = Bt + (size_t)(n0 + r) * ldb + (kt + c * 8);
                __builtin_amdgcn_global_load_lds(
                    (const __attribute__((address_space(1))) unsigned int*)g,
                    (__attribute__((address_space(3))) unsigned int*)&ldsbuf[8192 + (size_t)libase * 8],
                    16, 0, 0);
            }
        }
        __syncthreads();
#pragma unroll
        for (int kk = 0; kk < 2; ++kk) {
            short8 af[4], bfr[4];
#pragma unroll
            for (int f = 0; f < 4; ++f) {
                int r = wrow + f * 16 + (lane & 15);
                int c16 = kk * 4 + (lane >> 4);
                int ch = r * 8 + (c16 ^ (r & 7));
                af[f] = *(const short8*)&ldsbuf[ch * 8];
            }
#pragma unroll
            for (int f = 0; f < 4; ++f) {
                int r = wcol + f * 16 + (lane & 15);
                int c16 = kk * 4 + (lane >> 4);
                int ch = r * 8 + (c16 ^ (r & 7));
                bfr[f] = *(const short8*)&ldsbuf[8192 + ch * 8];
            }
#pragma unroll
            for (int i = 0; i < 4; ++i)
#pragma unroll
                for (int j = 0; j < 4; ++j)
                    acc[i][j] = __builtin_amdgcn_mfma_f32_16x16x32_bf16(af[i], bfr[j], acc[i][j], 0, 0, 0);
        }
        __syncthreads();
    }
#pragma unroll
    for (int i = 0; i < 4; ++i)
#pragma unroll
        for (int j = 0; j < 4; ++j)
#pragma unroll
            for (int q = 0; q < 4; ++q) {
                int row = m0 + wrow + i * 16 + (lane >> 4) * 4 + q;
                int col = n0 + wcol + j * 16 + (lane & 15);
                if (row < M) {
                    if (OUT_BF16) ((ushort_t*)Cv)[(size_t)row * ldc + col] = f2b(acc[i][j][q]);
                    else          ((float*)Cv)[(size_t)row * ldc + col] = acc[i][j][q];
                }
            }
}

// ---------------------------------------------------------------- fused agg (coop)
// one wave per node; rounds of 16 edges. Literal-index broadcasts via
// v_readlane (SGPR, no LDS pipe); cooperative ef distribution uses one shuffle.
#define RLI(v, l) __builtin_amdgcn_readlane((v), (l))
__global__ __launch_bounds__(256) void agg_coop(
    const ushort_t* __restrict__ PQ, ushort_t* __restrict__ X,
    const int4* __restrict__ esl, const int* __restrict__ offs,
    const float* __restrict__ eig, const float* __restrict__ h,
    const float* __restrict__ ef, const float* __restrict__ W_pre,
    const float* __restrict__ b_pre, float* __restrict__ scal, int Nn) {
    int tid = threadIdx.x;
    int wid = tid >> 6, lane = tid & 63;
    int n = blockIdx.x * 4 + wid;
    if (n >= Nn) return;
    int off0 = offs[n], off1 = offs[n + 1];
    int deg = off1 - off0;
    int d0 = lane * 2;

    f32x2 w3r[16];
#pragma unroll
    for (int j = 0; j < 16; ++j)
        w3r[j] = *(const f32x2*)&W_pre[(256 + j) * 128 + d0];

    uint_t qw = *(const uint_t*)&PQ[(size_t)n * 256 + 128 + d0];
    float2 bp = *(const float2*)&b_pre[d0];
    f32x2 qb;
    qb.x = b2f((ushort_t)(qw & 0xffff)) + bp.x;
    qb.y = b2f((ushort_t)(qw >> 16)) + bp.y;
    float eigd = eig[n * 2 + 1];

    f32x2 s = {0.f, 0.f}, ss = {0.f, 0.f}, av = {0.f, 0.f}, dv = {0.f, 0.f};
    f32x2 mx = {-1e30f, -1e30f}, mn = {1e30f, 1e30f};
    float den = 0.f;

    for (int q0 = off0; q0 < off1; q0 += 16) {
        int cnt = off1 - q0; if (cnt > 16) cnt = 16;
        int slot = q0 + (lane & 15);
        if (slot > off1 - 1) slot = off1 - 1;
        int4 rc = esl[slot];
        int eidL = __shfl(rc.y, lane >> 2);
        float4 efv = ((const float4*)ef)[(size_t)eidL * 4 + (lane & 3)];
        uint_t pw[16];
#pragma unroll
        for (int j = 0; j < 16; ++j) {
            if (j < cnt) {
                int sj = RLI(rc.x, j);
                pw[j] = *(const uint_t*)&PQ[(size_t)sj * 256 + d0];
            }
        }
#pragma unroll
        for (int j = 0; j < 16; ++j) {
            if (j < cnt) {
                f32x2 acc = qb;
#pragma unroll
                for (int b = 0; b < 4; ++b) {
                    float va = __uint_as_float((uint_t)RLI(__float_as_int(efv.x), 4 * j + b));
                    float vb = __uint_as_float((uint_t)RLI(__float_as_int(efv.y), 4 * j + b));
                    float vc = __uint_as_float((uint_t)RLI(__float_as_int(efv.z), 4 * j + b));
                    float vd = __uint_as_float((uint_t)RLI(__float_as_int(efv.w), 4 * j + b));
                    acc = va * w3r[4 * b + 0] + acc;
                    acc = vb * w3r[4 * b + 1] + acc;
                    acc = vc * w3r[4 * b + 2] + acc;
                    acc = vd * w3r[4 * b + 3] + acc;
                }
                f32x2 m;
                m.x = b2f((ushort_t)(pw[j] & 0xffff));
                m.y = b2f((ushort_t)(pw[j] >> 16));
                m = m + acc;
                float dd = __int_as_float(RLI(rc.z, j)) - eigd;
                float ad = fabsf(dd);
                s = s + m; ss = m * m + ss;
                mx = __builtin_elementwise_max(mx, m);
                mn = __builtin_elementwise_min(mn, m);
                av = ad * m + av; dv = dd * m + dv;
                den += ad;
            }
        }
    }

    size_t xb = (size_t)n * 896 + 128;
    float2 hv = *(const float2*)&h[(size_t)n * 128 + d0];
    float o[12];
    if (deg > 0) {
        float inv = 1.f / (float)deg;
        float mean0 = s.x * inv, mean1 = s.y * inv;
        float var0 = fmaxf(ss.x * inv - mean0 * mean0, 0.f);
        float var1 = fmaxf(ss.y * inv - mean1 * mean1, 0.f);
        float sd0 = sqrtf(var0 + 1e-5f), sd1 = sqrtf(var1 + 1e-5f);
        float idn = 1.f / (den + 1e-8f);
        o[0] = mean0; o[1] = mean1; o[2] = mx.x; o[3] = mx.y; o[4] = mn.x; o[5] = mn.y;
        o[6] = sd0; o[7] = sd1; o[8] = av.x * idn; o[9] = av.y * idn;
        o[10] = dv.x * idn - hv.x; o[11] = dv.y * idn - hv.y;
    } else {
#pragma unroll
        for (int k = 0; k < 12; ++k) o[k] = 0.f;
    }
#pragma unroll
    for (int a = 0; a < 6; ++a) {
        uint_t w = (uint_t)f2b(o[2 * a]) | ((uint_t)f2b(o[2 * a + 1]) << 16);
        *(uint_t*)&X[xb + a * 128 + d0] = w;
    }
    if (lane == 0) {
        float degc = deg > 0 ? (float)deg : 1.f;
        float logd = logf(degc + 1.f);
        scal[n * 2] = logd * (1.f / 2.772588722239781f);
        scal[n * 2 + 1] = 2.772588722239781f / logd;
    }
}

// ---------------------------------------------------------------- epilogue (bf16 O3)
__global__ __launch_bounds__(256) void epilogue_kernel(
    const ushort_t* __restrict__ O3, const float* __restrict__ h,
    const float* __restrict__ snorm, const float* __restrict__ scal,
    const float* __restrict__ b_post, float* __restrict__ out, int Nn) {
    int g = blockIdx.x * 256 + threadIdx.x;
    if (g >= Nn * 32) return;
    int n = g >> 5, c4 = (g & 31) * 4;
    float a = scal[n * 2], b = scal[n * 2 + 1], sn = snorm[n];
    const ushort_t* base = O3 + (size_t)n * 384 + c4;
    ushort4 u1 = *(const ushort4*)base;
    ushort4 u2 = *(const ushort4*)(base + 128);
    ushort4 u3 = *(const ushort4*)(base + 256);
    float4 bp = *(const float4*)&b_post[c4];
    float4 hv = *(const float4*)&h[(size_t)n * 128 + c4];
    float4 r;
    r.x = fmaxf((b2f(u1.x) + a * b2f(u2.x) + b * b2f(u3.x) + bp.x) * sn, 0.f) + hv.x;
    r.y = fmaxf((b2f(u1.y) + a * b2f(u2.y) + b * b2f(u3.y) + bp.y) * sn, 0.f) + hv.y;
    r.z = fmaxf((b2f(u1.z) + a * b2f(u2.z) + b * b2f(u3.z) + bp.z) * sn, 0.f) + hv.z;
    r.w = fmaxf((b2f(u1.w) + a * b2f(u2.w) + b * b2f(u3.w) + bp.w) * sn, 0.f) + hv.w;
    *(float4*)&out[(size_t)n * 128 + c4] = r;
}

// ---------------------------------------------------------------- launch
extern "C" void kernel_launch(void* const* d_in, const int* in_sizes, int n_in,
                              void* d_out, int out_size, void* d_ws, size_t ws_size,
                              hipStream_t stream) {
    const float* h      = (const float*)d_in[0];
    const float* ef     = (const float*)d_in[1];
    const float* eig    = (const float*)d_in[2];
    const float* snorm  = (const float*)d_in[3];
    const int*   src    = (const int*)d_in[4];
    const int*   dst    = (const int*)d_in[5];
    const float* W_pre  = (const float*)d_in[6];
    const float* b_pre  = (const float*)d_in[7];
    const float* W_post = (const float*)d_in[8];
    const float* b_post = (const float*)d_in[9];
    int Nn = in_sizes[0] / 128;
    int E  = in_sizes[4];
    float* out = (float*)d_out;

    char* ws = (char*)d_ws;
    size_t off = 0;
    auto alloc = [&](size_t bytes) {
        size_t o = off;
        off = (off + bytes + 255) & ~(size_t)255;
        return o;
    };
    size_t o_counts  = alloc(((size_t)Nn + 1) * 4);
    size_t o_cursors = alloc((size_t)Nn * 4);
    size_t o_bsum    = alloc(65 * 4);
    size_t o_esl     = alloc((size_t)E * 16);
    size_t o_PQ      = alloc((size_t)Nn * 256 * 2);
    size_t o_X       = alloc((size_t)Nn * 896 * 2);
    size_t o_O3      = alloc((size_t)Nn * 384 * 2);
    size_t o_scal    = alloc((size_t)Nn * 2 * 4);
    size_t o_wb      = alloc(256 * 128 * 2);
    size_t o_wc      = alloc(384 * 896 * 2);
    (void)ws_size;

    int*      counts  = (int*)(ws + o_counts);
    int*      cursors = (int*)(ws + o_cursors);
    int*      bsum    = (int*)(ws + o_bsum);
    int4*     esl     = (int4*)(ws + o_esl);
    ushort_t* PQ      = (ushort_t*)(ws + o_PQ);
    ushort_t* X       = (ushort_t*)(ws + o_X);
    ushort_t* O3      = (ushort_t*)(ws + o_O3);
    float*    scal    = (float*)(ws + o_scal);
    ushort_t* WbT     = (ushort_t*)(ws + o_wb);
    ushort_t* WcT     = (ushort_t*)(ws + o_wc);

    int prep_items = (Nn + 1) + 256 * 128 + 384 * 896 + Nn * 32;
    prep_kernel<<<(prep_items + 255) / 256, 256, 0, stream>>>(W_pre, W_post, h,
                                                              counts, WbT, WcT, X, Nn);
    hist_kernel<<<(E + 255) / 256, 256, 0, stream>>>(dst, counts, E);
    int nb = (Nn + 1023) / 1024;
    scanA_kernel<<<nb, 256, 0, stream>>>(counts, cursors, bsum, Nn);
    scanB_kernel<<<1, 64, 0, stream>>>(bsum, nb);
    scanC_kernel<<<(Nn + 255) / 256, 256, 0, stream>>>(cursors, bsum, counts, Nn, nb);
    scatter_kernel<<<(E + 255) / 256, 256, 0, stream>>>(dst, src, eig, cursors, esl, E);

    int mt = (Nn + 127) / 128;
    gemm_bt<1><<<mt * 2, 256, 0, stream>>>(X, 896, WbT, 128, (void*)PQ, 256, Nn, 128, 2);

    agg_coop<<<(Nn + 3) / 4, 256, 0, stream>>>(PQ, X, esl, counts, eig, h, ef,
                                               W_pre, b_pre, scal, Nn);

    gemm_bt<1><<<mt * 3, 256, 0, stream>>>(X, 896, WcT, 896, (void*)O3, 384, Nn, 896, 3);

    epilogue_kernel<<<(Nn * 32 + 255) / 256, 256, 0, stream>>>(O3, h, snorm, scal, b_post,
                                                               out, Nn);
}